// Round 1
// baseline (1386.608 us; speedup 1.0000x reference)
//
#include <hip/hip_runtime.h>
#include <math.h>

// AdaptGNN: B=8, N=2048, D=H=128, 3 layers.
// Layer: t = h@W + b; invn = 1/max(||t||,eps); O[p,:] = invn[p] * sum_q ew[p,q]*invn[q]*(t[p]. t[q]) * t[q,:]; relu unless last.
// fp32 baseline, fused flash-style aggregation (cos matrix never materialized).

static constexpr int kB = 8;
static constexpr int kN = 2048;
static constexpr int kH = 128;
static constexpr int kTP = 32;   // P rows per block
static constexpr int kTQ = 64;   // Q rows per tile
static constexpr int kLDH = 129; // padded LDS stride for h tiles (conflict-free)
static constexpr int kLDS = 65;  // padded LDS stride for S tile

// ---------------- linear + row-norm kernel ----------------
// grid: B*N/16 blocks, 256 threads. Each block: 16 rows.
// thread (r = tid>>4, cg = tid&15) computes cols {cg + 16*j}, j<8.
__global__ __launch_bounds__(256) void linear_norm_kernel(
    const float* __restrict__ in, const float* __restrict__ W,
    const float* __restrict__ bias, float* __restrict__ t,
    float* __restrict__ invn)
{
    __shared__ float xs[16 * kLDH];  // 16 rows x 128, stride 129
    __shared__ float Ws[64 * kH];    // half of W (32 KB), staged twice

    const int tid = threadIdx.x;
    const int rowbase = blockIdx.x * 16;

    // stage x rows (coalesced float4 global -> padded LDS)
    {
        const float4* s4 = (const float4*)(in + (size_t)rowbase * kH);
        for (int i = tid; i < 16 * kH / 4; i += 256) {
            float4 v = s4[i];
            int fl = i * 4;
            float* dst = &xs[(fl >> 7) * kLDH + (fl & 127)];
            dst[0] = v.x; dst[1] = v.y; dst[2] = v.z; dst[3] = v.w;
        }
    }

    const int cg = tid & 15;
    const int r  = tid >> 4;

    float acc[8];
#pragma unroll
    for (int j = 0; j < 8; ++j) acc[j] = 0.f;

    for (int half = 0; half < 2; ++half) {
        __syncthreads();  // xs staged (half 0) / previous Ws consumed (half 1)
        {
            const float4* w4 = (const float4*)(W + half * 64 * kH);
            float4* d4 = (float4*)Ws;
            for (int i = tid; i < 64 * kH / 4; i += 256) d4[i] = w4[i];
        }
        __syncthreads();
#pragma unroll 4
        for (int d = 0; d < 64; ++d) {
            float xv = xs[r * kLDH + half * 64 + d];
#pragma unroll
            for (int j = 0; j < 8; ++j)
                acc[j] += xv * Ws[d * kH + cg + 16 * j];
        }
    }

    // bias + sum of squares
    float val[8];
    float ss = 0.f;
#pragma unroll
    for (int j = 0; j < 8; ++j) {
        val[j] = acc[j] + bias[cg + 16 * j];
        ss += val[j] * val[j];
    }
    // reduce across the 16 threads of this row (consecutive lanes)
    ss += __shfl_xor(ss, 1, 16);
    ss += __shfl_xor(ss, 2, 16);
    ss += __shfl_xor(ss, 4, 16);
    ss += __shfl_xor(ss, 8, 16);

    float inv = 1.f / fmaxf(sqrtf(ss), 1e-12f);

    const int row = rowbase + r;
    float* trow = t + (size_t)row * kH;
#pragma unroll
    for (int j = 0; j < 8; ++j) trow[cg + 16 * j] = val[j];
    if (cg == 0) invn[row] = inv;
}

// ---------------- fused aggregation kernel ----------------
// O[p,c] = invn[p] * sum_q (ew[p,q] * invn[q] * dot(t[p],t[q])) * t[q,c]
// grid: (N/kTP, B), 128 threads (2 waves).
__global__ __launch_bounds__(128) void agg_kernel(
    const float* __restrict__ t, const float* __restrict__ invn,
    const float* __restrict__ ew, float* __restrict__ out, int do_relu)
{
    __shared__ float hP[kTP * kLDH];   // 16.5 KB
    __shared__ float hQ[kTQ * kLDH];   // 33 KB
    __shared__ float Sm[kTP * kLDS];   // 8.3 KB
    __shared__ float invP[kTP];
    __shared__ float invQ[kTQ];

    const int b = blockIdx.y;
    const int pbase = blockIdx.x * kTP;
    const int tid = threadIdx.x;

    const float* tb  = t + (size_t)b * kN * kH;
    const float* ewb = ew + (size_t)b * kN * kN;

    // stage hP (32 x 128)
    {
        const float4* src = (const float4*)(tb + (size_t)pbase * kH);
        for (int i = tid; i < kTP * kH / 4; i += 128) {
            float4 v = src[i];
            int fl = i * 4;
            float* dst = &hP[(fl >> 7) * kLDH + (fl & 127)];
            dst[0] = v.x; dst[1] = v.y; dst[2] = v.z; dst[3] = v.w;
        }
        if (tid < kTP) invP[tid] = invn[b * kN + pbase + tid];
    }

    // S-phase mapping: tp = tid>>4 (0..7) -> p = tp*4+i ; tq = tid&15 -> q = tq*4+j
    const int tq = tid & 15;
    const int tp = tid >> 4;
    // O-phase mapping: tr = tid>>4 (0..7) -> p = tr*4+i ; tc = tid&15 -> c = tc+16*j
    const int tc = tid & 15;
    const int tr = tid >> 4;

    float oacc[4][8];
#pragma unroll
    for (int i = 0; i < 4; ++i)
#pragma unroll
        for (int j = 0; j < 8; ++j) oacc[i][j] = 0.f;

    __syncthreads();

    for (int qt = 0; qt < kN / kTQ; ++qt) {
        const int qbase = qt * kTQ;
        // stage hQ (64 x 128)
        {
            const float4* src = (const float4*)(tb + (size_t)qbase * kH);
            for (int i = tid; i < kTQ * kH / 4; i += 128) {
                float4 v = src[i];
                int fl = i * 4;
                float* dst = &hQ[(fl >> 7) * kLDH + (fl & 127)];
                dst[0] = v.x; dst[1] = v.y; dst[2] = v.z; dst[3] = v.w;
            }
            if (tid < kTQ) invQ[tid] = invn[b * kN + qbase + tid];
        }
        __syncthreads();

        // ---- S phase: dacc[i][j] = dot(hP[tp*4+i], hQ[tq*4+j]) ----
        float dacc[4][4];
#pragma unroll
        for (int i = 0; i < 4; ++i)
#pragma unroll
            for (int j = 0; j < 4; ++j) dacc[i][j] = 0.f;

#pragma unroll 4
        for (int d = 0; d < kH; ++d) {
            float a0 = hP[(tp * 4 + 0) * kLDH + d];
            float a1 = hP[(tp * 4 + 1) * kLDH + d];
            float a2 = hP[(tp * 4 + 2) * kLDH + d];
            float a3 = hP[(tp * 4 + 3) * kLDH + d];
            float b0 = hQ[(tq * 4 + 0) * kLDH + d];
            float b1 = hQ[(tq * 4 + 1) * kLDH + d];
            float b2 = hQ[(tq * 4 + 2) * kLDH + d];
            float b3 = hQ[(tq * 4 + 3) * kLDH + d];
            dacc[0][0] += a0 * b0; dacc[0][1] += a0 * b1; dacc[0][2] += a0 * b2; dacc[0][3] += a0 * b3;
            dacc[1][0] += a1 * b0; dacc[1][1] += a1 * b1; dacc[1][2] += a1 * b2; dacc[1][3] += a1 * b3;
            dacc[2][0] += a2 * b0; dacc[2][1] += a2 * b1; dacc[2][2] += a2 * b2; dacc[2][3] += a2 * b3;
            dacc[3][0] += a3 * b0; dacc[3][1] += a3 * b1; dacc[3][2] += a3 * b2; dacc[3][3] += a3 * b3;
        }

        // S = dacc * ew * invQ  (invP factored out to epilogue)
#pragma unroll
        for (int i = 0; i < 4; ++i) {
            const int p = tp * 4 + i;
            float4 e = *(const float4*)&ewb[(size_t)(pbase + p) * kN + qbase + tq * 4];
            Sm[p * kLDS + tq * 4 + 0] = dacc[i][0] * e.x * invQ[tq * 4 + 0];
            Sm[p * kLDS + tq * 4 + 1] = dacc[i][1] * e.y * invQ[tq * 4 + 1];
            Sm[p * kLDS + tq * 4 + 2] = dacc[i][2] * e.z * invQ[tq * 4 + 2];
            Sm[p * kLDS + tq * 4 + 3] = dacc[i][3] * e.w * invQ[tq * 4 + 3];
        }
        __syncthreads();

        // ---- O phase: oacc[i][j] += S[p][q] * hQ[q][c] ----
#pragma unroll 4
        for (int q = 0; q < kTQ; ++q) {
            float sv0 = Sm[(tr * 4 + 0) * kLDS + q];
            float sv1 = Sm[(tr * 4 + 1) * kLDS + q];
            float sv2 = Sm[(tr * 4 + 2) * kLDS + q];
            float sv3 = Sm[(tr * 4 + 3) * kLDS + q];
            float hv[8];
#pragma unroll
            for (int j = 0; j < 8; ++j) hv[j] = hQ[q * kLDH + tc + 16 * j];
#pragma unroll
            for (int j = 0; j < 8; ++j) {
                oacc[0][j] += sv0 * hv[j];
                oacc[1][j] += sv1 * hv[j];
                oacc[2][j] += sv2 * hv[j];
                oacc[3][j] += sv3 * hv[j];
            }
        }
        __syncthreads();  // before next q-tile overwrites hQ / Sm
    }

    // epilogue: scale by invn[p], relu, store
    float* ob = out + (size_t)b * kN * kH;
#pragma unroll
    for (int i = 0; i < 4; ++i) {
        const int p = tr * 4 + i;
        const float s = invP[p];
#pragma unroll
        for (int j = 0; j < 8; ++j) {
            float v = oacc[i][j] * s;
            if (do_relu) v = fmaxf(v, 0.f);
            ob[(size_t)(pbase + p) * kH + tc + 16 * j] = v;
        }
    }
}

extern "C" void kernel_launch(void* const* d_in, const int* in_sizes, int n_in,
                              void* d_out, int out_size, void* d_ws, size_t ws_size,
                              hipStream_t stream) {
    const float* x  = (const float*)d_in[0];
    const float* ew = (const float*)d_in[1];
    const float* W[3]    = {(const float*)d_in[2], (const float*)d_in[4], (const float*)d_in[6]};
    const float* bias[3] = {(const float*)d_in[3], (const float*)d_in[5], (const float*)d_in[7]};

    float* tbuf = (float*)d_ws;                       // [B,N,H] post-linear h
    float* hbuf = tbuf + (size_t)kB * kN * kH;        // [B,N,H] layer output
    float* invn = hbuf + (size_t)kB * kN * kH;        // [B,N]   1/max(||row||,eps)
    float* out  = (float*)d_out;

    const float* cur = x;
    for (int layer = 0; layer < 3; ++layer) {
        linear_norm_kernel<<<kB * kN / 16, 256, 0, stream>>>(cur, W[layer], bias[layer], tbuf, invn);
        float* o = (layer == 2) ? out : hbuf;
        agg_kernel<<<dim3(kN / kTP, kB), 128, 0, stream>>>(tbuf, invn, ew, o, layer < 2 ? 1 : 0);
        cur = hbuf;
    }
}

// Round 2
// 545.672 us; speedup vs baseline: 2.5411x; 2.5411x over previous
//
#include <hip/hip_runtime.h>
#include <hip/hip_bf16.h>
#include <math.h>

// AdaptGNN: B=8, N=2048, D=H=128, 3 layers.
// Layer: t = h@W + b (fp32); invn = 1/max(||t||,eps);
//        S' = ew .* (invP*invQ*(t.t^T));  O = S' @ t; relu unless last.
// Round 2: bf16 MFMA for both N^2 GEMMs; ew stays exact fp32 (multiplied into
// the fp32 MFMA accumulator). HBM-bound on the ew stream (134 MB/layer).

typedef __attribute__((ext_vector_type(8))) short bf16x8;   // 8 bf16 = 4 VGPRs
typedef __attribute__((ext_vector_type(4))) float f32x4;

static constexpr int kB = 8, kN = 2048, kH = 128;
static constexpr int kLDH = 129;  // fp32 LDS pad (linear kernel)
static constexpr int kSstr = 136; // S' LDS stride in bf16: 272 B -> 4-bank rotate/row -> 2-way (free)

// ---------------- linear + row-norm kernel ----------------
// t16 = bf16(h@W + b), invn = 1/max(||row||,eps) (norm computed in fp32)
__global__ __launch_bounds__(256) void linear_norm_kernel(
    const float* __restrict__ in, const float* __restrict__ W,
    const float* __restrict__ bias, ushort* __restrict__ t16,
    float* __restrict__ invn)
{
    __shared__ float xs[16 * kLDH];
    __shared__ float Ws[64 * kH];

    const int tid = threadIdx.x;
    const int rowbase = blockIdx.x * 16;

    {
        const float4* s4 = (const float4*)(in + (size_t)rowbase * kH);
        for (int i = tid; i < 16 * kH / 4; i += 256) {
            float4 v = s4[i];
            int fl = i * 4;
            float* dst = &xs[(fl >> 7) * kLDH + (fl & 127)];
            dst[0] = v.x; dst[1] = v.y; dst[2] = v.z; dst[3] = v.w;
        }
    }

    const int cg = tid & 15;
    const int r  = tid >> 4;

    float acc[8];
#pragma unroll
    for (int j = 0; j < 8; ++j) acc[j] = 0.f;

    for (int half = 0; half < 2; ++half) {
        __syncthreads();
        {
            const float4* w4 = (const float4*)(W + half * 64 * kH);
            float4* d4 = (float4*)Ws;
            for (int i = tid; i < 64 * kH / 4; i += 256) d4[i] = w4[i];
        }
        __syncthreads();
#pragma unroll 4
        for (int d = 0; d < 64; ++d) {
            float xv = xs[r * kLDH + half * 64 + d];
#pragma unroll
            for (int j = 0; j < 8; ++j)
                acc[j] += xv * Ws[d * kH + cg + 16 * j];
        }
    }

    float val[8];
    float ss = 0.f;
#pragma unroll
    for (int j = 0; j < 8; ++j) {
        val[j] = acc[j] + bias[cg + 16 * j];
        ss += val[j] * val[j];
    }
    ss += __shfl_xor(ss, 1, 16);
    ss += __shfl_xor(ss, 2, 16);
    ss += __shfl_xor(ss, 4, 16);
    ss += __shfl_xor(ss, 8, 16);

    float inv = 1.f / fmaxf(sqrtf(ss), 1e-12f);

    const int row = rowbase + r;
    ushort* trow = t16 + (size_t)row * kH;
#pragma unroll
    for (int j = 0; j < 8; ++j) {
        __hip_bfloat16 hb = __float2bfloat16(val[j]);
        trow[cg + 16 * j] = *reinterpret_cast<ushort*>(&hb);
    }
    if (cg == 0) invn[row] = inv;
}

// ---------------- transpose kernel: t16[b][q][d] -> tT[b][d][q] ----------------
__global__ __launch_bounds__(256) void transpose_kernel(
    const ushort* __restrict__ t, ushort* __restrict__ tT)
{
    __shared__ ushort tile[64][72];  // 144 B rows: 16B-aligned, 4-bank rotate
    const int b = blockIdx.z;
    const int qb = blockIdx.x * 64;
    const int db = blockIdx.y * 64;
    const int tid = threadIdx.x;
    const int r  = tid >> 3;         // 0..31
    const int cg = (tid & 7) * 8;    // 0..56
#pragma unroll
    for (int it = 0; it < 2; ++it) {
        const int row = r + 32 * it;
        bf16x8 v = *(const bf16x8*)&t[(size_t)(b * kN + qb + row) * kH + db + cg];
        *(bf16x8*)&tile[row][cg] = v;
    }
    __syncthreads();
#pragma unroll
    for (int it = 0; it < 2; ++it) {
        const int d = r + 32 * it;
        bf16x8 o;
#pragma unroll
        for (int j = 0; j < 8; ++j) o[j] = (short)tile[cg + j][d];
        *(bf16x8*)&tT[(size_t)(b * kH + db + d) * kN + qb + cg] = o;
    }
}

// ---------------- fused MFMA aggregation ----------------
// Per block: 64 P-rows, full q sweep in chunks of 128. 256 threads = 4 waves,
// wave grid 2(p) x 2(q/c). S-phase: S = tP.tQ^T (K=d). Epilogue: *ew*invP*invQ,
// bf16 -> LDS (A-layout source). O-phase: O += S' @ tQ (K=q), B-frags from tT.
__global__ __launch_bounds__(256) void agg_kernel(
    const ushort* __restrict__ t, const ushort* __restrict__ tT,
    const float* __restrict__ invn, const float* __restrict__ ew,
    float* __restrict__ out, int do_relu)
{
    __shared__ ushort Sp[64 * kSstr];  // 17.4 KB
    __shared__ float invPs[64];

    const int b = blockIdx.y;
    const int pbase = blockIdx.x * 64;
    const int tid = threadIdx.x;
    const int lane = tid & 63;
    const int wid = tid >> 6;
    const int wp = wid >> 1;     // p-half (0..1)
    const int wq = wid & 1;      // q/c-half (0..1)
    const int quad = lane >> 4;  // 0..3
    const int l16 = lane & 15;

    const ushort* tb  = t  + (size_t)b * kN * kH;
    const ushort* tTb = tT + (size_t)b * kH * kN;
    const float* ewb  = ew + (size_t)b * kN * kN;
    const float* invb = invn + b * kN;

    if (tid < 64) invPs[tid] = invb[pbase + tid];

    // preload hP A-fragments (reused across all q-tiles):
    // A[m=l16][k=quad*8+j] per 16x16x32 layout [m89-verified]
    bf16x8 Af[2][4];
#pragma unroll
    for (int i = 0; i < 2; ++i)
#pragma unroll
        for (int k = 0; k < 4; ++k)
            Af[i][k] = *(const bf16x8*)&tb[(size_t)(pbase + wp * 32 + i * 16 + l16) * kH + k * 32 + quad * 8];

    __syncthreads();
    float invPr[2][4];
#pragma unroll
    for (int i = 0; i < 2; ++i)
#pragma unroll
        for (int r = 0; r < 4; ++r)
            invPr[i][r] = invPs[wp * 32 + i * 16 + quad * 4 + r];

    f32x4 oacc[2][4];
#pragma unroll
    for (int i = 0; i < 2; ++i)
#pragma unroll
        for (int c = 0; c < 4; ++c)
            oacc[i][c] = (f32x4){0.f, 0.f, 0.f, 0.f};

    for (int qt = 0; qt < kN / 128; ++qt) {
        const int qbase = qt * 128;

        // hoisted: ew in C-fragment layout (coalesced 64B segments) + invQ
        float ewr[2][4][4];
#pragma unroll
        for (int i = 0; i < 2; ++i)
#pragma unroll
            for (int jt = 0; jt < 4; ++jt) {
                const int qcol = qbase + wq * 64 + jt * 16 + l16;
#pragma unroll
                for (int r = 0; r < 4; ++r)
                    ewr[i][jt][r] = ewb[(size_t)(pbase + wp * 32 + i * 16 + quad * 4 + r) * kN + qcol];
            }
        float invQr[4];
#pragma unroll
        for (int jt = 0; jt < 4; ++jt)
            invQr[jt] = invb[qbase + wq * 64 + jt * 16 + l16];

        // ---- S-phase: dacc[i][jt] = tP_tile_i . tQ_tile_jt^T ----
        f32x4 dacc[2][4];
#pragma unroll
        for (int i = 0; i < 2; ++i)
#pragma unroll
            for (int jt = 0; jt < 4; ++jt)
                dacc[i][jt] = (f32x4){0.f, 0.f, 0.f, 0.f};

#pragma unroll
        for (int k = 0; k < 4; ++k) {
            bf16x8 Bf[4];  // B[n=q=l16][k=d]: 16B contiguous from row-major t
#pragma unroll
            for (int jt = 0; jt < 4; ++jt)
                Bf[jt] = *(const bf16x8*)&tb[(size_t)(qbase + wq * 64 + jt * 16 + l16) * kH + k * 32 + quad * 8];
#pragma unroll
            for (int i = 0; i < 2; ++i)
#pragma unroll
                for (int jt = 0; jt < 4; ++jt)
                    dacc[i][jt] = __builtin_amdgcn_mfma_f32_16x16x32_bf16(Af[i][k], Bf[jt], dacc[i][jt], 0, 0, 0);
        }

        // ---- epilogue: S' = dacc * ew * invP * invQ -> bf16 -> LDS [p][q] ----
        // C-layout: col(q)=l16, row(p)=quad*4+reg [m89-verified]
#pragma unroll
        for (int i = 0; i < 2; ++i) {
            const int prow0 = wp * 32 + i * 16 + quad * 4;
#pragma unroll
            for (int jt = 0; jt < 4; ++jt) {
                const int qcol = wq * 64 + jt * 16 + l16;
#pragma unroll
                for (int r = 0; r < 4; ++r) {
                    float s = dacc[i][jt][r] * ewr[i][jt][r] * invPr[i][r] * invQr[jt];
                    __hip_bfloat16 hb = __float2bfloat16(s);
                    Sp[(prow0 + r) * kSstr + qcol] = *reinterpret_cast<ushort*>(&hb);
                }
            }
        }
        __syncthreads();

        // ---- O-phase: oacc[i][ct] += S'[rows i] @ tQ[:, cols ct] over q=128 ----
#pragma unroll
        for (int k = 0; k < 4; ++k) {
            bf16x8 Sa[2];  // A[m=p=l16][k=q]: from padded LDS (2-way, free)
#pragma unroll
            for (int i = 0; i < 2; ++i)
                Sa[i] = *(const bf16x8*)&Sp[(wp * 32 + i * 16 + l16) * kSstr + k * 32 + quad * 8];
            bf16x8 Bb[4];  // B[n=c=l16][k=q]: 16B contiguous from tT
#pragma unroll
            for (int ct = 0; ct < 4; ++ct)
                Bb[ct] = *(const bf16x8*)&tTb[(size_t)(wq * 64 + ct * 16 + l16) * kN + qbase + k * 32 + quad * 8];
#pragma unroll
            for (int i = 0; i < 2; ++i)
#pragma unroll
                for (int ct = 0; ct < 4; ++ct)
                    oacc[i][ct] = __builtin_amdgcn_mfma_f32_16x16x32_bf16(Sa[i], Bb[ct], oacc[i][ct], 0, 0, 0);
        }
        __syncthreads();
    }

    // ---- store O (+relu), coalesced 64B segments ----
    float* ob = out + (size_t)b * kN * kH;
#pragma unroll
    for (int i = 0; i < 2; ++i)
#pragma unroll
        for (int ct = 0; ct < 4; ++ct)
#pragma unroll
            for (int r = 0; r < 4; ++r) {
                const int p = pbase + wp * 32 + i * 16 + quad * 4 + r;
                const int c = wq * 64 + ct * 16 + l16;
                float v = oacc[i][ct][r];
                if (do_relu) v = fmaxf(v, 0.f);
                ob[(size_t)p * kH + c] = v;
            }
}

extern "C" void kernel_launch(void* const* d_in, const int* in_sizes, int n_in,
                              void* d_out, int out_size, void* d_ws, size_t ws_size,
                              hipStream_t stream) {
    const float* x  = (const float*)d_in[0];
    const float* ew = (const float*)d_in[1];
    const float* W[3]    = {(const float*)d_in[2], (const float*)d_in[4], (const float*)d_in[6]};
    const float* bias[3] = {(const float*)d_in[3], (const float*)d_in[5], (const float*)d_in[7]};

    // ws layout (16.07 MB total, same footprint as round 1):
    ushort* t16  = (ushort*)d_ws;                       // [B,N,H] bf16 post-linear
    ushort* tT16 = t16 + (size_t)kB * kN * kH;          // [B,H,N] bf16 transposed
    float*  invn = (float*)(tT16 + (size_t)kB * kN * kH); // [B,N]
    float*  hbuf = invn + (size_t)kB * kN;              // [B,N,H] fp32 layer output
    float*  out  = (float*)d_out;

    const float* cur = x;
    for (int layer = 0; layer < 3; ++layer) {
        linear_norm_kernel<<<kB * kN / 16, 256, 0, stream>>>(cur, W[layer], bias[layer], t16, invn);
        transpose_kernel<<<dim3(kN / 64, kH / 64, kB), 256, 0, stream>>>(t16, tT16);
        float* o = (layer == 2) ? out : hbuf;
        agg_kernel<<<dim3(kN / 64, kB), 256, 0, stream>>>(t16, tT16, invn, ew, o, layer < 2 ? 1 : 0);
        cur = hbuf;
    }
}